// Round 8
// baseline (609.623 us; speedup 1.0000x reference)
//
#include <hip/hip_runtime.h>
#include <hip/hip_bf16.h>
#include <math.h>

typedef __bf16 bf16;
typedef __bf16 bf16x4 __attribute__((ext_vector_type(4)));
typedef __bf16 bf16x8 __attribute__((ext_vector_type(8)));
typedef float f32x4 __attribute__((ext_vector_type(4)));

#define MFMA(a, b, c) __builtin_amdgcn_mfma_f32_16x16x32_bf16((a), (b), (c), 0, 0, 0)

constexpr int Bb  = 2;
constexpr int Hh  = 16;
constexpr int Ss  = 2048;
constexpr int KVv = 4096;
constexpr int Dd  = 64;
constexpr int Cc  = KVv - Ss;   // 2048
constexpr int HID = Hh * Dd;    // 1024

constexpr float QSCL = 0.125f * 1.44269504088896340736f;

constexpr size_t MASK_F4     = (size_t)Bb * Hh * Ss * KVv / 4;  // 67,108,864
constexpr size_t ATTNB_BYTES = (size_t)Bb * Ss * HID * 2;       // 8,388,608
constexpr size_t M1_F4       = 44000000;                        // attn-phase mask share
constexpr size_t M2_F4       = MASK_F4 - ATTNB_BYTES / 16;      // 66,584,576

// ---------------------------------------------------------------------------
// Mask range writer: 32 B per lane per iteration, nontemporal.
// Ranges are in float4 units; all callers pass even-sized ranges.
// ---------------------------------------------------------------------------
__device__ __forceinline__ void write_mask_range(
    float* __restrict__ mout, int mem, size_t lo4, size_t hi4,
    int mblk, int nmblk, int tid, int nthr)
{
    const int R = Cc + mem;
    const size_t lo = lo4 >> 1, hi = hi4 >> 1;   // units of 8 floats
    const size_t stride = (size_t)nmblk * nthr;
    for (size_t p = lo + (size_t)mblk * nthr + tid; p < hi; p += stride) {
        size_t flat = p * 8;
        int t = (int)(flat & (size_t)(KVv - 1));
        int s = (int)((flat >> 12) & (size_t)(Ss - 1));
        int thr = (s < mem) ? R : (s + Cc + 1);
        f32x4 v0, v1;
        v0[0] = (float)(t     >= thr); v0[1] = (float)(t + 1 >= thr);
        v0[2] = (float)(t + 2 >= thr); v0[3] = (float)(t + 3 >= thr);
        v1[0] = (float)(t + 4 >= thr); v1[1] = (float)(t + 5 >= thr);
        v1[2] = (float)(t + 6 >= thr); v1[3] = (float)(t + 7 >= thr);
        __builtin_nontemporal_store(v0, (f32x4*)(mout + flat));
        __builtin_nontemporal_store(v1, (f32x4*)(mout + flat + 4));
    }
}

// ---------------------------------------------------------------------------
// Attention tile body: stages K (convert) and V (transpose+convert) from fp32
// global into LDS; 128 q-rows/block, 8 waves, 16 rows/wave.
// ---------------------------------------------------------------------------
template <bool MASKED>
__device__ __forceinline__ void kv_tile(
    int t0, const float* __restrict__ kfp, const float* __restrict__ vfp,
    const bf16x8 qa[2], const int thr[4], int tid, int lr, int lg,
    bf16 (*__restrict__ Klds)[72], bf16 (*__restrict__ Vlds)[72],
    bf16 (*__restrict__ Pw)[72], f32x4 acco[4], float lsum[4])
{
    if (tid < 256) {
        // K[t0+row][c16..c16+15] fp32 -> Klds[row][c16..]
        const int row = tid >> 2, c16 = (tid & 3) * 16;
        const float* kp4 = kfp + (size_t)(t0 + row) * Dd + c16;
        float4 k0 = ((const float4*)kp4)[0];
        float4 k1 = ((const float4*)kp4)[1];
        float4 k2 = ((const float4*)kp4)[2];
        float4 k3 = ((const float4*)kp4)[3];
        bf16x8 lo, hi;
        lo[0] = (bf16)k0.x; lo[1] = (bf16)k0.y; lo[2] = (bf16)k0.z; lo[3] = (bf16)k0.w;
        lo[4] = (bf16)k1.x; lo[5] = (bf16)k1.y; lo[6] = (bf16)k1.z; lo[7] = (bf16)k1.w;
        hi[0] = (bf16)k2.x; hi[1] = (bf16)k2.y; hi[2] = (bf16)k2.z; hi[3] = (bf16)k2.w;
        hi[4] = (bf16)k3.x; hi[5] = (bf16)k3.y; hi[6] = (bf16)k3.z; hi[7] = (bf16)k3.w;
        *(bf16x8*)&Klds[row][c16]     = lo;
        *(bf16x8*)&Klds[row][c16 + 8] = hi;
    } else {
        // V[t0+r4+j][c4+i] fp32 -> Vlds[c4+i][r4+j]  (transpose)
        const int t2 = tid - 256;
        const int r4 = (t2 & 15) * 4, c4 = (t2 >> 4) * 4;
        const float* vb = vfp + (size_t)(t0 + r4) * Dd + c4;
        float4 a0 = *(const float4*)(vb);
        float4 a1 = *(const float4*)(vb + Dd);
        float4 a2 = *(const float4*)(vb + 2 * Dd);
        float4 a3 = *(const float4*)(vb + 3 * Dd);
        const float* f0 = (const float*)&a0;
        const float* f1 = (const float*)&a1;
        const float* f2 = (const float*)&a2;
        const float* f3 = (const float*)&a3;
#pragma unroll
        for (int i = 0; i < 4; ++i) {
            bf16x4 t;
            t[0] = (bf16)f0[i]; t[1] = (bf16)f1[i];
            t[2] = (bf16)f2[i]; t[3] = (bf16)f3[i];
            *(bf16x4*)&Vlds[c4 + i][r4] = t;
        }
    }
    __syncthreads();

    f32x4 accs[4];
#pragma unroll
    for (int kg = 0; kg < 4; ++kg) accs[kg] = (f32x4){0.f, 0.f, 0.f, 0.f};
    __builtin_amdgcn_s_setprio(1);
#pragma unroll
    for (int ks = 0; ks < 2; ++ks) {
#pragma unroll
        for (int kg = 0; kg < 4; ++kg) {
            bf16x8 kf = *(const bf16x8*)&Klds[kg * 16 + lr][ks * 32 + lg * 8];
            accs[kg] = MFMA(qa[ks], kf, accs[kg]);
        }
    }
    __builtin_amdgcn_s_setprio(0);

#pragma unroll
    for (int r = 0; r < 4; ++r) {
#pragma unroll
        for (int kg = 0; kg < 4; ++kg) {
            float sl = accs[kg][r];
            if (MASKED) {
                int tcol = t0 + kg * 16 + lr;
                sl = (tcol < thr[r]) ? sl : -1e30f;
            }
            accs[kg][r] = __builtin_amdgcn_exp2f(sl);
        }
        lsum[r] += (accs[0][r] + accs[1][r]) + (accs[2][r] + accs[3][r]);
#pragma unroll
        for (int kg = 0; kg < 4; ++kg)
            Pw[lg * 4 + r][kg * 16 + lr] = (bf16)accs[kg][r];
    }
    asm volatile("s_waitcnt lgkmcnt(0)" ::: "memory");

    __builtin_amdgcn_s_setprio(1);
#pragma unroll
    for (int ks = 0; ks < 2; ++ks) {
        bf16x8 pa = *(const bf16x8*)&Pw[lr][ks * 32 + lg * 8];
#pragma unroll
        for (int dg = 0; dg < 4; ++dg) {
            bf16x8 vf = *(const bf16x8*)&Vlds[dg * 16 + lr][ks * 32 + lg * 8];
            acco[dg] = MFMA(pa, vf, acco[dg]);
        }
    }
    __builtin_amdgcn_s_setprio(0);
    __syncthreads();
}

// ---------------------------------------------------------------------------
// Fused: blocks [0,512) = attention (XCD-swizzled, 128 q-rows each, direct
// fp32 K/V); blocks [512,...) write mask float4 range [0, M1_F4).
// ---------------------------------------------------------------------------
__global__ __launch_bounds__(512) void fused_attn_kernel(
    const float* __restrict__ q, const float* __restrict__ k,
    const float* __restrict__ v, const int* __restrict__ memp,
    bf16* __restrict__ attnb, float* __restrict__ mout)
{
    __shared__ __align__(16) bf16 Klds[64][72];
    __shared__ __align__(16) bf16 Vlds[64][72];
    __shared__ __align__(16) bf16 Plds[8][16][72];

    const int fid = blockIdx.x;
    const int mem = *memp;
    if (fid >= 512) {
        write_mask_range(mout, mem, 0, M1_F4, fid - 512, gridDim.x - 512,
                         threadIdx.x, 512);
        return;
    }
    // XCD swizzle: 4 heads per XCD, all 16 q-blocks of a head on one XCD.
    const int xcd = fid & 7;
    const int slot = fid >> 3;
    const int qblk = slot & 15;
    const int bh = (slot >> 4) * 8 + xcd;

    const int tid = threadIdx.x;
    const int w  = tid >> 6;
    const int l  = tid & 63;
    const int lr = l & 15;
    const int lg = l >> 4;
    const int q0 = qblk * 128;
    const int R = Cc + mem;

    const float* qp  = q + (size_t)bh * Ss * Dd;
    const float* kfp = k + (size_t)bh * KVv * Dd;
    const float* vfp = v + (size_t)bh * KVv * Dd;

    const int qrow = q0 + w * 16 + lr;
    bf16x8 qa[2];
#pragma unroll
    for (int ks = 0; ks < 2; ++ks) {
        const float* p8 = qp + (size_t)qrow * Dd + ks * 32 + lg * 8;
        float4 x0 = *(const float4*)p8;
        float4 x1 = *(const float4*)(p8 + 4);
        bf16x8 a;
        a[0] = (bf16)(x0.x * QSCL); a[1] = (bf16)(x0.y * QSCL);
        a[2] = (bf16)(x0.z * QSCL); a[3] = (bf16)(x0.w * QSCL);
        a[4] = (bf16)(x1.x * QSCL); a[5] = (bf16)(x1.y * QSCL);
        a[6] = (bf16)(x1.z * QSCL); a[7] = (bf16)(x1.w * QSCL);
        qa[ks] = a;
    }

    int thr[4];
#pragma unroll
    for (int r = 0; r < 4; ++r) {
        int qabs = q0 + w * 16 + lg * 4 + r;
        thr[r] = (qabs < mem) ? R : (qabs + Cc + 1);
    }
    const int qmaxb = q0 + 127;
    int kv_end = (qmaxb < mem) ? R : (qmaxb + Cc + 1);
    if (kv_end > KVv) kv_end = KVv;
    int thr_min = (q0 < mem) ? R : (q0 + Cc + 1);
    int p1_end = thr_min & ~63;
    if (p1_end > kv_end) p1_end = kv_end;

    f32x4 acco[4];
#pragma unroll
    for (int dg = 0; dg < 4; ++dg) acco[dg] = (f32x4){0.f, 0.f, 0.f, 0.f};
    float lsum[4] = {0.f, 0.f, 0.f, 0.f};

    for (int t0 = 0; t0 < p1_end; t0 += 64)
        kv_tile<false>(t0, kfp, vfp, qa, thr, tid, lr, lg, Klds, Vlds, Plds[w], acco, lsum);
    for (int t0 = p1_end; t0 < kv_end; t0 += 64)
        kv_tile<true>(t0, kfp, vfp, qa, thr, tid, lr, lg, Klds, Vlds, Plds[w], acco, lsum);

    const int b = bh >> 4, h = bh & 15;
#pragma unroll
    for (int r = 0; r < 4; ++r) {
        float s = lsum[r];
        s += __shfl_xor(s, 1);
        s += __shfl_xor(s, 2);
        s += __shfl_xor(s, 4);
        s += __shfl_xor(s, 8);
        float inv = 1.f / s;
        int qabs = q0 + w * 16 + lg * 4 + r;
        bf16* dst = attnb + (size_t)(b * Ss + qabs) * HID + h * Dd;
#pragma unroll
        for (int dg = 0; dg < 4; ++dg)
            dst[dg * 16 + lr] = (bf16)(acco[dg][r] * inv);
    }
}

// ---------------------------------------------------------------------------
// Fused: blocks [0,1024) = projection (W converted fp32->bf16 in staging,
// XCD-swizzled); rest write mask range [M1_F4, mhi).
// ---------------------------------------------------------------------------
__global__ __launch_bounds__(256) void fused_proj_kernel(
    const bf16* __restrict__ A, const float* __restrict__ W,
    const float* __restrict__ bias, float* __restrict__ out,
    const int* __restrict__ memp, float* __restrict__ mout, size_t mhi)
{
    __shared__ __align__(16) bf16 Alds[64][72];
    __shared__ __align__(16) bf16 Wlds[64][72];

    const int fid = blockIdx.x;
    if (fid >= 1024) {
        write_mask_range(mout, *memp, M1_F4, mhi, fid - 1024, gridDim.x - 1024,
                         threadIdx.x, 256);
        return;
    }
    const int xcd = fid & 7;
    const int slot = fid >> 3;
    const int o0 = ((slot & 1) * 8 + xcd) * 64;
    const int i0 = (slot >> 1) * 64;

    const int tid = threadIdx.x;
    const int w  = tid >> 6;
    const int l  = tid & 63;
    const int lr = l & 15;
    const int lg = l >> 4;

    f32x4 acc[4];
#pragma unroll
    for (int og = 0; og < 4; ++og) acc[og] = (f32x4){0.f, 0.f, 0.f, 0.f};

    for (int kc = 0; kc < HID; kc += 64) {
        const int row = tid >> 2, c16 = (tid & 3) * 16;
        const bf16* ap = A + (size_t)(i0 + row) * HID + kc + c16;
        bf16x8 a0 = ((const bf16x8*)ap)[0];
        bf16x8 a1 = ((const bf16x8*)ap)[1];
        const float* wp = W + (size_t)(o0 + row) * HID + kc + c16;
        float4 w0 = ((const float4*)wp)[0];
        float4 w1 = ((const float4*)wp)[1];
        float4 w2 = ((const float4*)wp)[2];
        float4 w3 = ((const float4*)wp)[3];
        bf16x8 wlo, whi;
        wlo[0] = (bf16)w0.x; wlo[1] = (bf16)w0.y; wlo[2] = (bf16)w0.z; wlo[3] = (bf16)w0.w;
        wlo[4] = (bf16)w1.x; wlo[5] = (bf16)w1.y; wlo[6] = (bf16)w1.z; wlo[7] = (bf16)w1.w;
        whi[0] = (bf16)w2.x; whi[1] = (bf16)w2.y; whi[2] = (bf16)w2.z; whi[3] = (bf16)w2.w;
        whi[4] = (bf16)w3.x; whi[5] = (bf16)w3.y; whi[6] = (bf16)w3.z; whi[7] = (bf16)w3.w;
        *(bf16x8*)&Alds[row][c16]     = a0;
        *(bf16x8*)&Alds[row][c16 + 8] = a1;
        *(bf16x8*)&Wlds[row][c16]     = wlo;
        *(bf16x8*)&Wlds[row][c16 + 8] = whi;
        __syncthreads();
        __builtin_amdgcn_s_setprio(1);
#pragma unroll
        for (int ks = 0; ks < 2; ++ks) {
            bf16x8 af = *(const bf16x8*)&Alds[w * 16 + lr][ks * 32 + lg * 8];
#pragma unroll
            for (int og = 0; og < 4; ++og) {
                bf16x8 wf = *(const bf16x8*)&Wlds[og * 16 + lr][ks * 32 + lg * 8];
                acc[og] = MFMA(af, wf, acc[og]);
            }
        }
        __builtin_amdgcn_s_setprio(0);
        __syncthreads();
    }

#pragma unroll
    for (int r = 0; r < 4; ++r) {
        int i = i0 + w * 16 + lg * 4 + r;
#pragma unroll
        for (int og = 0; og < 4; ++og) {
            int o = o0 + og * 16 + lr;
            __builtin_nontemporal_store(acc[og][r] + bias[o], &out[(size_t)i * HID + o]);
        }
    }
}

// ---------------------------------------------------------------------------
// Tail (fallback when attnb lives at the end of the mask region).
// ---------------------------------------------------------------------------
__global__ __launch_bounds__(256) void mask_tail_kernel(
    float* __restrict__ mout, const int* __restrict__ memp)
{
    write_mask_range(mout, *memp, M2_F4, MASK_F4, blockIdx.x, gridDim.x,
                     threadIdx.x, 256);
}

extern "C" void kernel_launch(void* const* d_in, const int* in_sizes, int n_in,
                              void* d_out, int out_size, void* d_ws, size_t ws_size,
                              hipStream_t stream)
{
    (void)in_sizes; (void)n_in; (void)out_size;
    const float* q    = (const float*)d_in[0];
    const float* k    = (const float*)d_in[1];
    const float* v    = (const float*)d_in[2];
    const int*   memp = (const int*)d_in[3];
    const float* W    = (const float*)d_in[4];
    const float* bias = (const float*)d_in[5];

    float* out     = (float*)d_out;
    float* maskout = out + (size_t)Bb * Ss * HID;

    const bool use_ws = ws_size >= ATTNB_BYTES;
    bf16* attnb = use_ws ? (bf16*)d_ws
                         : (bf16*)((char*)maskout + M2_F4 * 16);

    const size_t mhi = use_ws ? MASK_F4 : M2_F4;

    fused_attn_kernel<<<dim3(512 + 1024), 512, 0, stream>>>(q, k, v, memp, attnb, maskout);
    fused_proj_kernel<<<dim3(1024 + 512), 256, 0, stream>>>(attnb, W, bias, out, memp, maskout, mhi);
    if (!use_ws)
        mask_tail_kernel<<<dim3(128), 256, 0, stream>>>(maskout, memp);
}